// Round 11
// baseline (702.674 us; speedup 1.0000x reference)
//
#include <hip/hip_runtime.h>

constexpr int NN  = 100000;
constexpr int NE  = 1600000;
constexpr int D   = 128;
constexpr int H   = 32;
constexpr int CAP = 64;        // max in-degree bucket (P(overflow) ~ 1e-14)
constexpr int NTILE = 4;
constexpr int TILE_SZ = NN / NTILE;   // 25000 nodes = 3.2 MB of z -> fits 4MB per-XCD L2

// Journal:
//  r2: edge-parallel f32 atomics: 164us. r3/r9: node-gather (2 variants): 174/166us.
//  => ~1.6M random 128B row touches on 12.8MB array is memory-system-bound (~165us)
//     regardless of issue-side structure. This round: 4-pass source-window tiling so
//     gather hits per-XCD L2; agg accumulated sequentially with nontemporal stores.
//  f32 activations mandatory (BN near-dead channels amplify ~58x; see r7).

// ---- build bucket-CSR: slots[d*CAP + pos] = src, cnt[d] = degree ----
__global__ __launch_bounds__(256) void k_fill(const int* __restrict__ src,
                                              const int* __restrict__ dst,
                                              int* __restrict__ cnt,
                                              int* __restrict__ slots) {
    for (int e = blockIdx.x * blockDim.x + threadIdx.x; e < NE;
         e += gridDim.x * blockDim.x) {
        const int d = dst[e];
        const int pos = atomicAdd(&cnt[d], 1);
        if (pos < CAP) slots[d * CAP + pos] = src[e];
    }
}

// ---------------- z = x @ W (D -> H), f32 (verified r3/r9) ----------------
__global__ __launch_bounds__(256) void k_xw1(const float* __restrict__ x,
                                             const float* __restrict__ W,
                                             float* __restrict__ z) {
    __shared__ float Wl[D * H];  // 16 KB
    for (int i = threadIdx.x; i < D * H; i += blockDim.x) Wl[i] = W[i];
    __syncthreads();
    const int j = threadIdx.x & 31;
    const int g = threadIdx.x >> 5;
    const int groups = blockDim.x >> 5;
    for (int n = blockIdx.x * groups + g; n < NN; n += gridDim.x * groups) {
        const float* xr = x + (size_t)n * D;
        float acc = 0.f;
#pragma unroll 8
        for (int k = 0; k < D; ++k) acc = fmaf(xr[k], Wl[k * H + j], acc);
        z[n * H + j] = acc;
    }
}

// ---- tiled gather pass: agg[n][j] (+)= sum over slots with src in [lo,lo+TILE_SZ) ----
// 32-lane group per node; slot row values are uniform across the group so the
// in-window predicate is wave-uniform (no divergence); gathers are 128B rows
// from the L2-resident window.
__global__ __launch_bounds__(256) void k_gather(const float* __restrict__ z,
                                                const int* __restrict__ cnt,
                                                const int* __restrict__ slots,
                                                float* __restrict__ agg,
                                                int lo, int first) {
    const int j = threadIdx.x & 31;
    const int g = threadIdx.x >> 5;
    const int groups = blockDim.x >> 5;
    for (int n = blockIdx.x * groups + g; n < NN; n += gridDim.x * groups) {
        const int deg = min(cnt[n], CAP);
        const int* row = slots + n * CAP;     // 256B-aligned
        float t = 0.f;
        for (int e = 0; e < deg; e += 8) {
            const int4 a = *(const int4*)(row + e);
            const int4 b = *(const int4*)(row + e + 4);   // within CAP, predicated below
            if ((unsigned)(a.x - lo) < (unsigned)TILE_SZ)                 t += z[a.x * H + j];
            if (e + 1 < deg && (unsigned)(a.y - lo) < (unsigned)TILE_SZ)  t += z[a.y * H + j];
            if (e + 2 < deg && (unsigned)(a.z - lo) < (unsigned)TILE_SZ)  t += z[a.z * H + j];
            if (e + 3 < deg && (unsigned)(a.w - lo) < (unsigned)TILE_SZ)  t += z[a.w * H + j];
            if (e + 4 < deg && (unsigned)(b.x - lo) < (unsigned)TILE_SZ)  t += z[b.x * H + j];
            if (e + 5 < deg && (unsigned)(b.y - lo) < (unsigned)TILE_SZ)  t += z[b.y * H + j];
            if (e + 6 < deg && (unsigned)(b.z - lo) < (unsigned)TILE_SZ)  t += z[b.z * H + j];
            if (e + 7 < deg && (unsigned)(b.w - lo) < (unsigned)TILE_SZ)  t += z[b.w * H + j];
        }
        float* ap = agg + (size_t)n * H + j;
        if (first) {
            __builtin_nontemporal_store(t, ap);           // init (ws is poisoned)
        } else {
            __builtin_nontemporal_store(t + *ap, ap);
        }
    }
}

// ---- r1 = relu(relu(z_self + agg + b1a) @ W1b + b1b); col stats ----
// buf = agg on input, r1 on output (in-place, same index per thread).
__global__ __launch_bounds__(256) void k_mlp1(const float* __restrict__ z,
                                              float* __restrict__ buf,
                                              const float* __restrict__ b1a,
                                              const float* __restrict__ W1b,
                                              const float* __restrict__ b1b,
                                              float* __restrict__ gsum,
                                              float* __restrict__ gsq) {
    __shared__ float Wl[H * H];  // 4 KB
    __shared__ float lsum[H], lsq[H];
    for (int i = threadIdx.x; i < H * H; i += blockDim.x) Wl[i] = W1b[i];
    if (threadIdx.x < H) { lsum[threadIdx.x] = 0.f; lsq[threadIdx.x] = 0.f; }
    __syncthreads();
    const int j = threadIdx.x & 31;
    const int g = threadIdx.x >> 5;
    const int groups = blockDim.x >> 5;
    const float ba = b1a[j], bb = b1b[j];
    float psum = 0.f, psq = 0.f;
    for (int n = blockIdx.x * groups + g; n < NN; n += gridDim.x * groups) {
        float t = z[n * H + j] + buf[n * H + j] + ba;
        t = fmaxf(t, 0.f);
        float u = bb;
#pragma unroll
        for (int k = 0; k < H; ++k) u = fmaf(__shfl(t, k, 32), Wl[k * H + j], u);
        const float r = fmaxf(u, 0.f);
        buf[n * H + j] = r;
        psum += r;
        psq = fmaf(r, r, psq);
    }
    atomicAdd(&lsum[j], psum);
    atomicAdd(&lsq[j], psq);
    __syncthreads();
    if (threadIdx.x < H) {
        atomicAdd(&gsum[threadIdx.x], lsum[threadIdx.x]);
        atomicAdd(&gsq[threadIdx.x], lsq[threadIdx.x]);
    }
}

// ---------------- BN stats -> scale/shift ----------------
__global__ void k_finalize(const float* __restrict__ gsum, const float* __restrict__ gsq,
                           const float* __restrict__ gamma, const float* __restrict__ beta,
                           float* __restrict__ scale, float* __restrict__ shift, int C) {
    const int j = threadIdx.x;
    if (j < C) {
        const float mean = gsum[j] * (1.f / NN);
        const float var  = gsq[j] * (1.f / NN) - mean * mean;
        const float sc   = gamma[j] * rsqrtf(var + 1e-5f);
        scale[j] = sc;
        shift[j] = beta[j] - mean * sc;
    }
}

// ---------------- z2 = (r1*scale+shift) @ W2a, f32 (verified) ----------------
__global__ __launch_bounds__(256) void k_bn_w2a(const float* __restrict__ r1,
                                                const float* __restrict__ scale,
                                                const float* __restrict__ shift,
                                                const float* __restrict__ W2a,
                                                float* __restrict__ z2) {
    __shared__ float Wl[H * H];
    for (int i = threadIdx.x; i < H * H; i += blockDim.x) Wl[i] = W2a[i];
    __syncthreads();
    const int j = threadIdx.x & 31;
    const int g = threadIdx.x >> 5;
    const int groups = blockDim.x >> 5;
    const float sc = scale[j], sh = shift[j];
    for (int n = blockIdx.x * groups + g; n < NN; n += gridDim.x * groups) {
        const float y = fmaf(r1[n * H + j], sc, sh);
        float u = 0.f;
#pragma unroll
        for (int k = 0; k < H; ++k) u = fmaf(__shfl(y, k, 32), Wl[k * H + j], u);
        z2[n * H + j] = u;
    }
}

// ---- out = relu(relu(z2 + agg2 + b2a) @ W2b + b2b); col stats ----
// wave per node; both halves compute the same t (broadcast loads), each lane
// emits output cols {lane, lane+64}.
__global__ __launch_bounds__(256) void k_mlp2(const float* __restrict__ z2,
                                              const float* __restrict__ agg,
                                              const float* __restrict__ b2a,
                                              const float* __restrict__ W2b,
                                              const float* __restrict__ b2b,
                                              float* __restrict__ out,
                                              float* __restrict__ gsum,
                                              float* __restrict__ gsq) {
    __shared__ float Wl[H * D];  // 16 KB
    __shared__ float lsum[D], lsq[D];
    for (int i = threadIdx.x; i < H * D; i += blockDim.x) Wl[i] = W2b[i];
    if (threadIdx.x < D) { lsum[threadIdx.x] = 0.f; lsq[threadIdx.x] = 0.f; }
    __syncthreads();
    const int lane = threadIdx.x & 63;
    const int wid  = threadIdx.x >> 6;
    const int j    = lane & 31;
    const float ba  = b2a[j];
    const float bb0 = b2b[lane], bb1 = b2b[64 + lane];
    float ps0 = 0.f, pq0 = 0.f, ps1 = 0.f, pq1 = 0.f;
    const int nw = (gridDim.x * blockDim.x) >> 6;
    for (int n = blockIdx.x * 4 + wid; n < NN; n += nw) {
        float t = z2[(size_t)n * H + j] + agg[(size_t)n * H + j] + ba;
        t = fmaxf(t, 0.f);
        float u0 = bb0, u1 = bb1;
#pragma unroll
        for (int k = 0; k < H; ++k) {
            const float tk = __shfl(t, k, 32);
            u0 = fmaf(tk, Wl[k * D + lane], u0);
            u1 = fmaf(tk, Wl[k * D + 64 + lane], u1);
        }
        const float r0 = fmaxf(u0, 0.f), r1v = fmaxf(u1, 0.f);
        out[(size_t)n * D + lane]      = r0;
        out[(size_t)n * D + 64 + lane] = r1v;
        ps0 += r0;  pq0 = fmaf(r0, r0, pq0);
        ps1 += r1v; pq1 = fmaf(r1v, r1v, pq1);
    }
    atomicAdd(&lsum[lane], ps0);      atomicAdd(&lsq[lane], pq0);
    atomicAdd(&lsum[64 + lane], ps1); atomicAdd(&lsq[64 + lane], pq1);
    __syncthreads();
    if (threadIdx.x < D) {
        atomicAdd(&gsum[threadIdx.x], lsum[threadIdx.x]);
        atomicAdd(&gsq[threadIdx.x], lsq[threadIdx.x]);
    }
}

// ---------------- in-place BN apply on out (N x D), float4 ----------------
__global__ __launch_bounds__(256) void k_bn_out(float* __restrict__ out,
                                                const float* __restrict__ scale,
                                                const float* __restrict__ shift) {
    const int total = NN * D / 4;
    float4* o4 = (float4*)out;
    for (int i = blockIdx.x * blockDim.x + threadIdx.x; i < total;
         i += gridDim.x * blockDim.x) {
        float4 v = o4[i];
        const int c = (i & 31) * 4;
        v.x = fmaf(v.x, scale[c + 0], shift[c + 0]);
        v.y = fmaf(v.y, scale[c + 1], shift[c + 1]);
        v.z = fmaf(v.z, scale[c + 2], shift[c + 2]);
        v.w = fmaf(v.w, scale[c + 3], shift[c + 3]);
        o4[i] = v;
    }
}

extern "C" void kernel_launch(void* const* d_in, const int* in_sizes, int n_in,
                              void* d_out, int out_size, void* d_ws, size_t ws_size,
                              hipStream_t stream) {
    const float* x   = (const float*)d_in[0];
    const int*   ei  = (const int*)d_in[1];
    const float* W1a = (const float*)d_in[2];
    const float* b1a = (const float*)d_in[3];
    const float* W1b = (const float*)d_in[4];
    const float* b1b = (const float*)d_in[5];
    const float* g1  = (const float*)d_in[6];
    const float* be1 = (const float*)d_in[7];
    const float* W2a = (const float*)d_in[8];
    const float* b2a = (const float*)d_in[9];
    const float* W2b = (const float*)d_in[10];
    const float* b2b = (const float*)d_in[11];
    const float* g2  = (const float*)d_in[12];
    const float* be2 = (const float*)d_in[13];
    float* out = (float*)d_out;
    const int* src = ei;        // edge_index[0]
    const int* dst = ei + NE;   // edge_index[1]

    // workspace (floats): z | buf(agg/r1) | cnt(int NN) | st(640) | slots(int NN*CAP)
    // ~51.6 MB total, same footprint as r9 (proven).
    float* ws = (float*)d_ws;
    float* z    = ws;                        // NN*H  (z1, later z2)
    float* buf  = ws + (size_t)NN * H;       // NN*H  (agg -> r1 -> agg2)
    int*   cnt  = (int*)(ws + 2 * (size_t)NN * H);
    float* st   = ws + 2 * (size_t)NN * H + NN;
    int*   slots = (int*)(st + 640);
    float* gsum1 = st;        float* gsq1 = st + 32;
    float* sc1   = st + 64;   float* sh1  = st + 96;
    float* gsum2 = st + 128;  float* gsq2 = st + 256;
    float* sc2   = st + 384;  float* sh2  = st + 512;

    hipMemsetAsync(cnt, 0, (NN + 640) * sizeof(float), stream);

    // ----- graph build (shared by both layers) -----
    k_fill<<<2048, 256, 0, stream>>>(src, dst, cnt, slots);

    // ----- layer 1 -----
    k_xw1<<<2048, 256, 0, stream>>>(x, W1a, z);
    for (int t = 0; t < NTILE; ++t)
        k_gather<<<2048, 256, 0, stream>>>(z, cnt, slots, buf, t * TILE_SZ, t == 0);
    k_mlp1<<<2048, 256, 0, stream>>>(z, buf, b1a, W1b, b1b, gsum1, gsq1);
    k_finalize<<<1, 128, 0, stream>>>(gsum1, gsq1, g1, be1, sc1, sh1, H);

    // ----- layer 2 -----
    k_bn_w2a<<<2048, 256, 0, stream>>>(buf, sc1, sh1, W2a, z);   // z := z2
    for (int t = 0; t < NTILE; ++t)
        k_gather<<<2048, 256, 0, stream>>>(z, cnt, slots, buf, t * TILE_SZ, t == 0);
    k_mlp2<<<2048, 256, 0, stream>>>(z, buf, b2a, W2b, b2b, out, gsum2, gsq2);
    k_finalize<<<1, 128, 0, stream>>>(gsum2, gsq2, g2, be2, sc2, sh2, D);
    k_bn_out<<<2048, 256, 0, stream>>>(out, sc2, sh2);
}

// Round 13
// 692.284 us; speedup vs baseline: 1.0150x; 1.0150x over previous
//
#include <hip/hip_runtime.h>

constexpr int NN  = 100000;
constexpr int NE  = 1600000;
constexpr int D   = 128;
constexpr int H   = 32;

// Journal (measured):
//  random-touch ceiling ~10-12G touches/s governs: fill(1.6M rnd wr)=130us,
//  gather(1.6M rnd 128B rd)=165us, atomic scatter(rnd rd + 51.2M atomics)=164us.
//  Scatter == gather cost but needs NO fill/slots => drop CSR entirely (saves 130us).
//  f32 mandatory on BN path (near-dead channels amplify ~58x; r7).
//  All kernels below verbatim from passing rounds (r2 scatter, r11 the rest).

// ---------------- agg[dst] += z[src]  (H floats per edge) ---- [r2 verified]
__global__ __launch_bounds__(256) void k_scatter(const int* __restrict__ src,
                                                 const int* __restrict__ dst,
                                                 const float* __restrict__ z,
                                                 float* __restrict__ agg) {
    const int total = NE * H;  // 51.2M < 2^31
    for (int i = blockIdx.x * blockDim.x + threadIdx.x; i < total;
         i += gridDim.x * blockDim.x) {
        const int e = i >> 5;
        const int f = i & 31;
        const int s = src[e];
        const int d = dst[e];
        atomicAdd(&agg[d * H + f], z[s * H + f]);
    }
}

// ---------------- z = x @ W (D -> H), f32 ---- [r3/r9/r11 verified]
__global__ __launch_bounds__(256) void k_xw1(const float* __restrict__ x,
                                             const float* __restrict__ W,
                                             float* __restrict__ z) {
    __shared__ float Wl[D * H];  // 16 KB
    for (int i = threadIdx.x; i < D * H; i += blockDim.x) Wl[i] = W[i];
    __syncthreads();
    const int j = threadIdx.x & 31;
    const int g = threadIdx.x >> 5;
    const int groups = blockDim.x >> 5;
    for (int n = blockIdx.x * groups + g; n < NN; n += gridDim.x * groups) {
        const float* xr = x + (size_t)n * D;
        float acc = 0.f;
#pragma unroll 8
        for (int k = 0; k < D; ++k) acc = fmaf(xr[k], Wl[k * H + j], acc);
        z[n * H + j] = acc;
    }
}

// ---- r1 = relu(relu(z + agg + b1a) @ W1b + b1b); col stats ---- [r11 verified]
// buf = agg on input, r1 on output (in-place, same index per thread).
__global__ __launch_bounds__(256) void k_mlp1(const float* __restrict__ z,
                                              float* __restrict__ buf,
                                              const float* __restrict__ b1a,
                                              const float* __restrict__ W1b,
                                              const float* __restrict__ b1b,
                                              float* __restrict__ gsum,
                                              float* __restrict__ gsq) {
    __shared__ float Wl[H * H];  // 4 KB
    __shared__ float lsum[H], lsq[H];
    for (int i = threadIdx.x; i < H * H; i += blockDim.x) Wl[i] = W1b[i];
    if (threadIdx.x < H) { lsum[threadIdx.x] = 0.f; lsq[threadIdx.x] = 0.f; }
    __syncthreads();
    const int j = threadIdx.x & 31;
    const int g = threadIdx.x >> 5;
    const int groups = blockDim.x >> 5;
    const float ba = b1a[j], bb = b1b[j];
    float psum = 0.f, psq = 0.f;
    for (int n = blockIdx.x * groups + g; n < NN; n += gridDim.x * groups) {
        float t = z[n * H + j] + buf[n * H + j] + ba;
        t = fmaxf(t, 0.f);
        float u = bb;
#pragma unroll
        for (int k = 0; k < H; ++k) u = fmaf(__shfl(t, k, 32), Wl[k * H + j], u);
        const float r = fmaxf(u, 0.f);
        buf[n * H + j] = r;
        psum += r;
        psq = fmaf(r, r, psq);
    }
    atomicAdd(&lsum[j], psum);
    atomicAdd(&lsq[j], psq);
    __syncthreads();
    if (threadIdx.x < H) {
        atomicAdd(&gsum[threadIdx.x], lsum[threadIdx.x]);
        atomicAdd(&gsq[threadIdx.x], lsq[threadIdx.x]);
    }
}

// ---------------- BN stats -> scale/shift ---- [verified]
__global__ void k_finalize(const float* __restrict__ gsum, const float* __restrict__ gsq,
                           const float* __restrict__ gamma, const float* __restrict__ beta,
                           float* __restrict__ scale, float* __restrict__ shift, int C) {
    const int j = threadIdx.x;
    if (j < C) {
        const float mean = gsum[j] * (1.f / NN);
        const float var  = gsq[j] * (1.f / NN) - mean * mean;
        const float sc   = gamma[j] * rsqrtf(var + 1e-5f);
        scale[j] = sc;
        shift[j] = beta[j] - mean * sc;
    }
}

// ---------------- z2 = (r1*scale+shift) @ W2a, f32 ---- [verified]
__global__ __launch_bounds__(256) void k_bn_w2a(const float* __restrict__ r1,
                                                const float* __restrict__ scale,
                                                const float* __restrict__ shift,
                                                const float* __restrict__ W2a,
                                                float* __restrict__ z2) {
    __shared__ float Wl[H * H];
    for (int i = threadIdx.x; i < H * H; i += blockDim.x) Wl[i] = W2a[i];
    __syncthreads();
    const int j = threadIdx.x & 31;
    const int g = threadIdx.x >> 5;
    const int groups = blockDim.x >> 5;
    const float sc = scale[j], sh = shift[j];
    for (int n = blockIdx.x * groups + g; n < NN; n += gridDim.x * groups) {
        const float y = fmaf(r1[n * H + j], sc, sh);
        float u = 0.f;
#pragma unroll
        for (int k = 0; k < H; ++k) u = fmaf(__shfl(y, k, 32), Wl[k * H + j], u);
        z2[n * H + j] = u;
    }
}

// ---- out = relu(relu(z2 + agg2 + b2a) @ W2b + b2b); col stats ---- [r11 verified]
__global__ __launch_bounds__(256) void k_mlp2(const float* __restrict__ z2,
                                              const float* __restrict__ agg,
                                              const float* __restrict__ b2a,
                                              const float* __restrict__ W2b,
                                              const float* __restrict__ b2b,
                                              float* __restrict__ out,
                                              float* __restrict__ gsum,
                                              float* __restrict__ gsq) {
    __shared__ float Wl[H * D];  // 16 KB
    __shared__ float lsum[D], lsq[D];
    for (int i = threadIdx.x; i < H * D; i += blockDim.x) Wl[i] = W2b[i];
    if (threadIdx.x < D) { lsum[threadIdx.x] = 0.f; lsq[threadIdx.x] = 0.f; }
    __syncthreads();
    const int lane = threadIdx.x & 63;
    const int wid  = threadIdx.x >> 6;
    const int j    = lane & 31;
    const float ba  = b2a[j];
    const float bb0 = b2b[lane], bb1 = b2b[64 + lane];
    float ps0 = 0.f, pq0 = 0.f, ps1 = 0.f, pq1 = 0.f;
    const int nw = (gridDim.x * blockDim.x) >> 6;
    for (int n = blockIdx.x * 4 + wid; n < NN; n += nw) {
        float t = z2[(size_t)n * H + j] + agg[(size_t)n * H + j] + ba;
        t = fmaxf(t, 0.f);
        float u0 = bb0, u1 = bb1;
#pragma unroll
        for (int k = 0; k < H; ++k) {
            const float tk = __shfl(t, k, 32);
            u0 = fmaf(tk, Wl[k * D + lane], u0);
            u1 = fmaf(tk, Wl[k * D + 64 + lane], u1);
        }
        const float r0 = fmaxf(u0, 0.f), r1v = fmaxf(u1, 0.f);
        out[(size_t)n * D + lane]      = r0;
        out[(size_t)n * D + 64 + lane] = r1v;
        ps0 += r0;  pq0 = fmaf(r0, r0, pq0);
        ps1 += r1v; pq1 = fmaf(r1v, r1v, pq1);
    }
    atomicAdd(&lsum[lane], ps0);      atomicAdd(&lsq[lane], pq0);
    atomicAdd(&lsum[64 + lane], ps1); atomicAdd(&lsq[64 + lane], pq1);
    __syncthreads();
    if (threadIdx.x < D) {
        atomicAdd(&gsum[threadIdx.x], lsum[threadIdx.x]);
        atomicAdd(&gsq[threadIdx.x], lsq[threadIdx.x]);
    }
}

// ---------------- in-place BN apply on out (N x D), float4 ---- [verified]
__global__ __launch_bounds__(256) void k_bn_out(float* __restrict__ out,
                                                const float* __restrict__ scale,
                                                const float* __restrict__ shift) {
    const int total = NN * D / 4;
    float4* o4 = (float4*)out;
    for (int i = blockIdx.x * blockDim.x + threadIdx.x; i < total;
         i += gridDim.x * blockDim.x) {
        float4 v = o4[i];
        const int c = (i & 31) * 4;
        v.x = fmaf(v.x, scale[c + 0], shift[c + 0]);
        v.y = fmaf(v.y, scale[c + 1], shift[c + 1]);
        v.z = fmaf(v.z, scale[c + 2], shift[c + 2]);
        v.w = fmaf(v.w, scale[c + 3], shift[c + 3]);
        o4[i] = v;
    }
}

extern "C" void kernel_launch(void* const* d_in, const int* in_sizes, int n_in,
                              void* d_out, int out_size, void* d_ws, size_t ws_size,
                              hipStream_t stream) {
    const float* x   = (const float*)d_in[0];
    const int*   ei  = (const int*)d_in[1];
    const float* W1a = (const float*)d_in[2];
    const float* b1a = (const float*)d_in[3];
    const float* W1b = (const float*)d_in[4];
    const float* b1b = (const float*)d_in[5];
    const float* g1  = (const float*)d_in[6];
    const float* be1 = (const float*)d_in[7];
    const float* W2a = (const float*)d_in[8];
    const float* b2a = (const float*)d_in[9];
    const float* W2b = (const float*)d_in[10];
    const float* b2b = (const float*)d_in[11];
    const float* g2  = (const float*)d_in[12];
    const float* be2 = (const float*)d_in[13];
    float* out = (float*)d_out;
    const int* src = ei;        // edge_index[0]
    const int* dst = ei + NE;   // edge_index[1]

    // workspace (floats): z | buf | st(640).  ~25.6 MB (well under proven budget).
    float* ws  = (float*)d_ws;
    float* z   = ws;                      // NN*H (z1, later z2)
    float* buf = ws + (size_t)NN * H;     // NN*H (agg1 -> r1 -> agg2)
    float* st  = ws + 2 * (size_t)NN * H; // 640 floats
    float* gsum1 = st;        float* gsq1 = st + 32;
    float* sc1   = st + 64;   float* sh1  = st + 96;
    float* gsum2 = st + 128;  float* gsq2 = st + 256;
    float* sc2   = st + 384;  float* sh2  = st + 512;

    // ----- layer 1 -----
    hipMemsetAsync(buf, 0, (size_t)NN * H * sizeof(float) + 640 * sizeof(float),
                   stream);                                  // agg1 + stats
    k_xw1<<<2048, 256, 0, stream>>>(x, W1a, z);
    k_scatter<<<4096, 256, 0, stream>>>(src, dst, z, buf);   // agg1
    k_mlp1<<<2048, 256, 0, stream>>>(z, buf, b1a, W1b, b1b, gsum1, gsq1);  // buf := r1
    k_finalize<<<1, 128, 0, stream>>>(gsum1, gsq1, g1, be1, sc1, sh1, H);

    // ----- layer 2 -----
    k_bn_w2a<<<2048, 256, 0, stream>>>(buf, sc1, sh1, W2a, z);  // z := z2
    hipMemsetAsync(buf, 0, (size_t)NN * H * sizeof(float), stream);  // agg2
    k_scatter<<<4096, 256, 0, stream>>>(src, dst, z, buf);
    k_mlp2<<<2048, 256, 0, stream>>>(z, buf, b2a, W2b, b2b, out, gsum2, gsq2);
    k_finalize<<<1, 128, 0, stream>>>(gsum2, gsq2, g2, be2, sc2, sh2, D);
    k_bn_out<<<2048, 256, 0, stream>>>(out, sc2, sh2);
}